// Round 1
// 187.671 us; speedup vs baseline: 1.0052x; 1.0052x over previous
//
#include <hip/hip_runtime.h>
#include <stdint.h>

#define GAMMA 0.002f
#define MDIM 4096
#define NDIM 8192
#define KDIM 512

typedef short v8s __attribute__((ext_vector_type(8)));
typedef float v4f __attribute__((ext_vector_type(4)));

__device__ __forceinline__ unsigned short f32_to_bf16_rne(float f) {
    union { float f; uint32_t u; } v; v.f = f;
    uint32_t u = v.u;
    return (unsigned short)((u + 0x7fffu + ((u >> 16) & 1u)) >> 16);
}

__device__ __forceinline__ void gl_lds16(const void* g, void* l) {
    __builtin_amdgcn_global_load_lds(
        (const __attribute__((address_space(1))) uint32_t*)g,
        (__attribute__((address_space(3))) uint32_t*)l, 16, 0, 0);
}

// One block per row: convert 512 fp32 -> bf16 (RNE) and emit -gamma*sum(x^2).
__global__ __launch_bounds__(256) void convert_rows(
    const float* __restrict__ in, unsigned short* __restrict__ outb,
    float* __restrict__ neg_g_sq) {
    int row = blockIdx.x;
    const float* src = in + (size_t)row * KDIM;
    unsigned short* dst = outb + (size_t)row * KDIM;
    int t = threadIdx.x;
    float2 f = ((const float2*)src)[t];
    ushort2 b;
    b.x = f32_to_bf16_rne(f.x);
    b.y = f32_to_bf16_rne(f.y);
    ((ushort2*)dst)[t] = b;
    float s = f.x * f.x + f.y * f.y;
    #pragma unroll
    for (int off = 32; off > 0; off >>= 1) s += __shfl_down(s, off, 64);
    __shared__ float red[4];
    if ((t & 63) == 0) red[t >> 6] = s;
    __syncthreads();
    if (t == 0) neg_g_sq[row] = -GAMMA * (red[0] + red[1] + red[2] + red[3]);
}

// 256x256 tile, BK=64, 8 waves (2M x 4N), double-buffered 128 KiB LDS,
// 4-phase-per-K-tile pipeline with counted vmcnt(6), T2 XOR-swizzle, T5 setprio.
// C[m,n] = exp(arow[m] + ccol[n] + 2*gamma*dot(x[m], sv[n]))
#define QUAD(MH, NH)                                                          \
  do {                                                                        \
    __builtin_amdgcn_s_setprio(1);                                            \
    _Pragma("unroll")                                                         \
    for (int kk = 0; kk < 2; ++kk) {                                          \
      _Pragma("unroll")                                                       \
      for (int i2 = 0; i2 < 4; ++i2) {                                        \
        _Pragma("unroll")                                                     \
        for (int j2 = 0; j2 < 2; ++j2) {                                      \
          acc[(MH)*4 + i2][(NH)*2 + j2] =                                     \
              __builtin_amdgcn_mfma_f32_16x16x32_bf16(                        \
                  bf[(NH)*2 + j2][kk], af[i2][kk],                            \
                  acc[(MH)*4 + i2][(NH)*2 + j2], 0, 0, 0);                    \
        }                                                                     \
      }                                                                       \
    }                                                                         \
    __builtin_amdgcn_s_setprio(0);                                            \
  } while (0)

__global__ __launch_bounds__(512, 2) void rbf_gemm(
    const unsigned short* __restrict__ A,   // [4096,512] bf16
    const unsigned short* __restrict__ B,   // [8192,512] bf16
    const float* __restrict__ arow,         // [4096]  = -g*||x||^2
    const float* __restrict__ ccol,         // [8192]  = -g*||sv||^2
    float* __restrict__ out) {

    // LDS layout per buffer (64 KiB, 2 buffers):
    //  +0      A-half0 (rows 0-127   of A tile, [128][64] bf16, swizzled)
    //  +16384  A-half1 (rows 128-255)
    //  +32768  B-half0 (rows 0-127 of B tile)
    //  +49152  B-half1
    __shared__ __align__(16) char smem[131072];

    const int tid  = threadIdx.x;
    const int lane = tid & 63;
    const int wave = tid >> 6;          // 0..7
    const int wm   = wave >> 2;         // 0..1 : 128-row slice
    const int wn   = wave & 3;          // 0..3 : 64-col slice

    // bijective XCD swizzle (512 = 8*64)
    const int bid  = blockIdx.x;
    const int swz  = ((bid & 7) << 6) | (bid >> 3);
    const int row0 = (swz >> 5) << 8;   // 0..3840
    const int col0 = (swz & 31) << 8;   // 0..7936

    // ---- staging (global -> linear LDS, source pre-inverse-swizzled) ----
    // thread covers rows (tid>>3) and 64+(tid>>3) of a 128-row half, 16B at
    // col chunk (tid&7); swizzle col ^= ((row&7)<<4).
    const int rA   = tid >> 3;
    const int colS = ((tid & 7) << 4) ^ ((rA & 7) << 4);
    const char* aSrc = (const char*)A + ((size_t)(row0 + rA) << 10) + colS;
    const char* bSrc = (const char*)B + ((size_t)(col0 + rA) << 10) + colS;

    auto stageA = [&](int tt, int h) {
        const char* s = aSrc + tt * 128 + h * 131072;            // k-off + 128 rows
        char* d = smem + ((tt & 1) << 16) + h * 16384 + tid * 16;
        gl_lds16(s, d);
        gl_lds16(s + 65536, d + 8192);                           // +64 rows
    };
    auto stageB = [&](int tt, int h) {
        const char* s = bSrc + tt * 128 + h * 131072;
        char* d = smem + ((tt & 1) << 16) + 32768 + h * 16384 + tid * 16;
        gl_lds16(s, d);
        gl_lds16(s + 65536, d + 8192);
    };

    // ---- fragment read addresses (swizzled) ----
    const int l15   = lane & 15;
    const int colK0 = ((lane >> 4) ^ (lane & 7)) << 4;       // kk=0 col bytes
    const int aBase0 = wm * 16384 + l15 * 128 + colK0;
    const int aBase1 = aBase0 ^ 64;                          // kk=1
    const int bBase0 = 32768 + (wn >> 1) * 16384 + (wn & 1) * 8192
                       + l15 * 128 + colK0;
    const int bBase1 = bBase0 ^ 64;

    v4f acc[8][4];
    #pragma unroll
    for (int i = 0; i < 8; ++i)
        #pragma unroll
        for (int j = 0; j < 4; ++j) acc[i][j] = (v4f)0.0f;

    v8s af[4][2];   // current m-half fragments
    v8s bf[4][2];   // all 4 n-fragments of current tile

    // prologue: issue 7 half-tiles: B0(0) B1(0) A0(0) A1(0) B0(1) B1(1) A0(1)
    stageB(0, 0); stageB(0, 1); stageA(0, 0); stageA(0, 1);
    stageB(1, 0); stageB(1, 1); stageA(1, 0);
    asm volatile("s_waitcnt vmcnt(6)" ::: "memory");   // tile 0 fully landed
    __builtin_amdgcn_s_barrier();

    #pragma unroll
    for (int t = 0; t < 8; ++t) {
        const int bufo = (t & 1) << 16;
        // ---- phase 0: ds_read A-mh0 + all B; stage A1(t+1); quad(0,0) ----
        #pragma unroll
        for (int i2 = 0; i2 < 4; ++i2) {
            af[i2][0] = *(const v8s*)(smem + bufo + aBase0 + i2 * 2048);
            af[i2][1] = *(const v8s*)(smem + bufo + aBase1 + i2 * 2048);
        }
        #pragma unroll
        for (int j = 0; j < 4; ++j) {
            bf[j][0] = *(const v8s*)(smem + bufo + bBase0 + j * 2048);
            bf[j][1] = *(const v8s*)(smem + bufo + bBase1 + j * 2048);
        }
        if (t + 1 < 8) stageA(t + 1, 1);
        __builtin_amdgcn_s_barrier();
        __builtin_amdgcn_sched_barrier(0);
        QUAD(0, 0);
        __builtin_amdgcn_s_barrier();
        // ---- phase 1: stage B0(t+2); quad(0,1) ----
        if (t + 2 < 8) stageB(t + 2, 0);
        __builtin_amdgcn_s_barrier();
        __builtin_amdgcn_sched_barrier(0);
        QUAD(0, 1);
        __builtin_amdgcn_s_barrier();
        // ---- phase 2: ds_read A-mh1; stage B1(t+2); quad(1,0) ----
        #pragma unroll
        for (int i2 = 0; i2 < 4; ++i2) {
            af[i2][0] = *(const v8s*)(smem + bufo + aBase0 + 8192 + i2 * 2048);
            af[i2][1] = *(const v8s*)(smem + bufo + aBase1 + 8192 + i2 * 2048);
        }
        if (t + 2 < 8) stageB(t + 2, 1);
        __builtin_amdgcn_s_barrier();
        __builtin_amdgcn_sched_barrier(0);
        QUAD(1, 0);
        __builtin_amdgcn_s_barrier();
        // ---- phase 3: stage A0(t+2); quad(1,1); counted vmcnt ----
        if (t + 2 < 8) stageA(t + 2, 0);
        __builtin_amdgcn_s_barrier();
        __builtin_amdgcn_sched_barrier(0);
        QUAD(1, 1);
        if (t < 6)       asm volatile("s_waitcnt vmcnt(6)" ::: "memory");
        else if (t == 6) asm volatile("s_waitcnt vmcnt(0)" ::: "memory");
        __builtin_amdgcn_s_barrier();
    }

    // ---- epilogue: biases to (now free) LDS, exp, float4 stores ----
    float* sb = (float*)smem;              // [0..255]=arow slice, [256..511]=ccol
    if (tid < 256) sb[tid] = arow[row0 + tid];
    else           sb[tid] = ccol[col0 + tid - 256];
    __syncthreads();

    const float tg = 2.0f * GAMMA;
    const int g4 = (lane >> 4) << 2;       // 0,4,8,12 : col sub-block
    #pragma unroll
    for (int i = 0; i < 8; ++i) {
        const int r_l = wm * 128 + i * 16 + l15;      // local out row
        const float ra = sb[r_l];
        float* gp = out + (size_t)(row0 + r_l) * NDIM + (col0 + wn * 64 + g4);
        #pragma unroll
        for (int j = 0; j < 4; ++j) {
            v4f o;
            #pragma unroll
            for (int v = 0; v < 4; ++v) {
                const int c_l = wn * 64 + j * 16 + g4 + v;
                o[v] = __expf(fmaf(tg, acc[i][j][v], ra + sb[256 + c_l]));
            }
            *(v4f*)(gp + j * 16) = o;
        }
    }
}

extern "C" void kernel_launch(void* const* d_in, const int* in_sizes, int n_in,
                              void* d_out, int out_size, void* d_ws, size_t ws_size,
                              hipStream_t stream) {
    const float* x  = (const float*)d_in[0];   // [4096,512]
    const float* sv = (const float*)d_in[1];   // [8192,512]
    float* out = (float*)d_out;

    // ws layout: xb (4 MiB) | svb (8 MiB) | arow (16 KiB) | ccol (32 KiB)
    unsigned short* xb  = (unsigned short*)d_ws;
    unsigned short* svb = xb + (size_t)MDIM * KDIM;
    float* arow = (float*)(svb + (size_t)NDIM * KDIM);
    float* ccol = arow + MDIM;

    hipLaunchKernelGGL(convert_rows, dim3(MDIM), dim3(256), 0, stream, x, xb, arow);
    hipLaunchKernelGGL(convert_rows, dim3(NDIM), dim3(256), 0, stream, sv, svb, ccol);
    hipLaunchKernelGGL(rbf_gemm, dim3((MDIM / 256) * (NDIM / 256)), dim3(512), 0,
                       stream, xb, svb, arow, ccol, out);
}